// Round 2
// baseline (364.461 us; speedup 1.0000x reference)
//
#include <hip/hip_runtime.h>
#include <math.h>

#define Bq 4
#define Hq 512
#define Nq 64
#define Lq 2048
#define PARAM (Hq*Nq)   // 32768

typedef float v2f __attribute__((ext_vector_type(2)));

// ---------------------------------------------------------------------------
// Phase 1: per-(h,n) parameter prep.
//   w  = exp(dt*A)                (complex, A = -exp(log_A_real) + i*A_imag)
//   dB = B * (w-1)/A
//   CB = C * dB ;  store a = 2*Re(CB), b = -2*Im(CB) so y += a*sr + b*si
// ---------------------------------------------------------------------------
__global__ void prep_kernel(const float* __restrict__ log_dt,
                            const float* __restrict__ log_A_real,
                            const float* __restrict__ A_imag,
                            const float* __restrict__ B_re, const float* __restrict__ B_im,
                            const float* __restrict__ C_re, const float* __restrict__ C_im,
                            float* __restrict__ wr_, float* __restrict__ wi_,
                            float* __restrict__ a0, float* __restrict__ b0,
                            float* __restrict__ a1, float* __restrict__ b1) {
    int idx = blockIdx.x * blockDim.x + threadIdx.x;
    if (idx >= PARAM) return;
    int h = idx >> 6;
    float dt = expf(log_dt[h]);
    float Ar = -expf(log_A_real[idx]);
    float Ai = A_imag[idx];
    float er = expf(Ar * dt);
    float wr = er * cosf(Ai * dt);
    float wi = er * sinf(Ai * dt);
    wr_[idx] = wr; wi_[idx] = wi;
    float mr = wr - 1.0f, mi = wi;
    float den = Ar * Ar + Ai * Ai;
    float qr = (mr * Ar + mi * Ai) / den;
    float qi = (mi * Ar - mr * Ai) / den;
    float Br = B_re[idx], Bi = B_im[idx];
    float dBr = Br * qr - Bi * qi;
    float dBi = Br * qi + Bi * qr;
    float cr = C_re[idx], ci = C_im[idx];
    a0[idx] =  2.0f * (cr * dBr - ci * dBi);
    b0[idx] = -2.0f * (cr * dBi + ci * dBr);
    cr = C_re[PARAM + idx]; ci = C_im[PARAM + idx];
    a1[idx] =  2.0f * (cr * dBr - ci * dBi);
    b1[idx] = -2.0f * (cr * dBi + ci * dBr);
}

// ---------------------------------------------------------------------------
// Phase 2: LayerNorm over channel dim H for each (b,l).
// block = 256 = 64 l-lanes x 4 h-groups; grid = B * (L/64) = 128. Coalesced
// 256B rows per h per group.
// ---------------------------------------------------------------------------
__global__ __launch_bounds__(256)
void ln_kernel(const float* __restrict__ x, const float* __restrict__ lnw,
               const float* __restrict__ lnb, float* __restrict__ z) {
    int b  = blockIdx.x >> 5;          // L/64 = 32 tiles per batch
    int l0 = (blockIdx.x & 31) * 64;
    int tx = threadIdx.x & 63;         // l within tile
    int ty = threadIdx.x >> 6;         // h group 0..3
    const float* xb = x + (size_t)b * Hq * Lq;
    float s = 0.f, s2 = 0.f;
    for (int h = ty; h < Hq; h += 4) {
        float v = xb[h * Lq + l0 + tx];
        s += v; s2 += v * v;
    }
    __shared__ float rs_[4][64], r2_[4][64], mu_s[64], sg_s[64];
    rs_[ty][tx] = s; r2_[ty][tx] = s2;
    __syncthreads();
    if (ty == 0) {
        float a = rs_[0][tx] + rs_[1][tx] + rs_[2][tx] + rs_[3][tx];
        float c = r2_[0][tx] + r2_[1][tx] + r2_[2][tx] + r2_[3][tx];
        float mu = a * (1.0f / Hq);
        float var = c * (1.0f / Hq) - mu * mu;
        mu_s[tx] = mu;
        sg_s[tx] = rsqrtf(var + 1e-5f);
    }
    __syncthreads();
    float mu = mu_s[tx], rs = sg_s[tx];
    float* zb = z + (size_t)b * Hq * Lq;
    for (int h = ty; h < Hq; h += 4) {
        float v = xb[h * Lq + l0 + tx];
        zb[h * Lq + l0 + tx] = (v - mu) * rs * lnw[h] + lnb[h];
    }
}

// ---------------------------------------------------------------------------
// Phase 3: fused bidirectional SSM scan + activation epilogue.
// One wave per (b,h); lane n = state index; packed fp32 carries BOTH
// directions (component 0 = fwd, 1 = bwd). Both dirs: update-then-output;
// bwd emission offset by one (y1[t-1] = proj(r'_t), y1[L-1] = 0).
// Tail: u = gelu_tanh(y0 + y1 + D*z) in-place into y0 (L2-hot re-read).
// ---------------------------------------------------------------------------
__global__ __launch_bounds__(64)
void scan_kernel(const float* __restrict__ z,
                 const float* __restrict__ wr_, const float* __restrict__ wi_,
                 const float* __restrict__ a0, const float* __restrict__ b0,
                 const float* __restrict__ a1, const float* __restrict__ b1,
                 const float* __restrict__ Dv,
                 float* __restrict__ y0, float* __restrict__ y1) {
    int bh = blockIdx.x;               // 0..B*H-1
    int h = bh & (Hq - 1);
    int n = threadIdx.x;
    int pidx = h * Nq + n;
    float wr = wr_[pidx], wi = wi_[pidx];
    v2f wr2 = { wr, wr }, wi2 = { wi, wi };
    v2f pa = { a0[pidx], a1[pidx] };
    v2f pb = { b0[pidx], b1[pidx] };

    // [64][33] b32 tiles: writes (fixed k) and reads (fixed j) are 2-way
    // bank aliasing only = free (m136); k/j index folds into imm offsets.
    __shared__ float tile_f[64][33];
    __shared__ float tile_b[64][33];
    __shared__ v2f zp[32];             // interleaved {z_fwd, z_bwd} per k

    const float* zz = z + (size_t)bh * Lq;
    float* y0r = y0 + (size_t)bh * Lq;
    float* y1r = y1 + (size_t)bh * Lq;

    v2f sr = {0.f, 0.f}, si = {0.f, 0.f};
    int tloc = n & 31, ih = n >> 5;

    for (int q0 = 0; q0 < Lq; q0 += 32) {
        if (n < 32) ((float*)zp)[2 * n]            = zz[q0 + n];
        else        ((float*)zp)[2 * (n - 32) + 1] = zz[Lq - 1 - q0 - (n - 32)];
        __syncthreads();
        #pragma unroll
        for (int k = 0; k < 32; ++k) {
            v2f zt = zp[k];                                  // b64 broadcast
            v2f t1 = __builtin_elementwise_fma(wi2, si, -zt); // wi*si - z
            v2f t2 = wi2 * sr;
            sr = __builtin_elementwise_fma(wr2, sr, -t1);     // wr*sr-wi*si+z
            si = __builtin_elementwise_fma(wr2, si, t2);
            v2f p = __builtin_elementwise_fma(pa, sr, pb * si);
            tile_f[n][k] = p.x;
            tile_b[n][k] = p.y;
        }
        __syncthreads();
        float af = 0.f, ab = 0.f;
        #pragma unroll
        for (int j = 0; j < 32; ++j) {
            af += tile_f[ih * 32 + j][tloc];
            ab += tile_b[ih * 32 + j][tloc];
        }
        af += __shfl_xor(af, 32, 64);
        ab += __shfl_xor(ab, 32, 64);
        if (n < 32) {
            y0r[q0 + n] = af;
        } else {
            int pos = Lq - 2 - q0 - (n - 32);
            if (pos >= 0) y1r[pos] = ab;
        }
        // no 3rd barrier needed: next zp write happens after this barrier's
        // phase; tile rewrite is fenced by next iteration's first barrier.
    }
    __syncthreads();
    // ---- activation tail: u = gelu(y0 + y1 + D*z), in-place into y0 ----
    float d = Dv[h];
    for (int t = n; t < Lq; t += 64) {
        float v0 = y0r[t];
        float v1 = (t == Lq - 1) ? 0.f : y1r[t];
        float v = v0 + v1 + d * zz[t];
        float g = 0.7978845608028654f * (v + 0.044715f * v * v * v);
        g = fminf(fmaxf(g, -15.f), 15.f);                 // avoid inf/NaN
        float e = __expf(2.0f * g);
        float th = (e - 1.0f) * __builtin_amdgcn_rcpf(e + 1.0f);
        y0r[t] = 0.5f * v * (1.0f + th);
    }
}

// ---------------------------------------------------------------------------
// Phase 5: out[b,o,l] = bias[o] + x[b,o,l] + sum_h W[o,h]*u[b,h,l]
// fp32 tiled GEMM: block tile 128(o) x 64(l), 256 threads, 8x4 microtile.
// ---------------------------------------------------------------------------
__global__ __launch_bounds__(256)
void gemm_kernel(const float* __restrict__ u, const float* __restrict__ W,
                 const float* __restrict__ bias, const float* __restrict__ x,
                 float* __restrict__ out) {
    int l0 = blockIdx.x * 64;
    int o0 = blockIdx.y * 128;
    int b  = blockIdx.z;
    int tid = threadIdx.x;
    __shared__ float Ws[16][129];   // [k][o]
    __shared__ float Us[16][65];    // [k][l]
    const float* ub = u + (size_t)b * Hq * Lq;
    float acc[8][4] = {};
    int wo = tid >> 4, wl = tid & 15;
    for (int k0 = 0; k0 < Hq; k0 += 16) {
        {
            int j  = tid & 15;       // k
            int ib = tid >> 4;       // o base
            #pragma unroll
            for (int r = 0; r < 8; ++r) {
                int i = ib + 16 * r;
                Ws[j][i] = W[(size_t)(o0 + i) * Hq + k0 + j];
            }
            int li = tid & 63;
            int jb = tid >> 6;
            #pragma unroll
            for (int r = 0; r < 4; ++r) {
                int j2 = jb + 4 * r;
                Us[j2][li] = ub[(size_t)(k0 + j2) * Lq + l0 + li];
            }
        }
        __syncthreads();
        #pragma unroll
        for (int j = 0; j < 16; ++j) {
            float av[8], bv[4];
            #pragma unroll
            for (int i = 0; i < 8; ++i) av[i] = Ws[j][8 * wo + i];
            #pragma unroll
            for (int i = 0; i < 4; ++i) bv[i] = Us[j][4 * wl + i];
            #pragma unroll
            for (int io = 0; io < 8; ++io)
                #pragma unroll
                for (int il = 0; il < 4; ++il)
                    acc[io][il] = fmaf(av[io], bv[il], acc[io][il]);
        }
        __syncthreads();
    }
    #pragma unroll
    for (int io = 0; io < 8; ++io) {
        int o = o0 + 8 * wo + io;
        float bo = bias[o];
        size_t base = ((size_t)b * Hq + o) * Lq + l0 + 4 * wl;
        const float4 xr = *(const float4*)(x + base);
        float4 r;
        r.x = acc[io][0] + bo + xr.x;
        r.y = acc[io][1] + bo + xr.y;
        r.z = acc[io][2] + bo + xr.z;
        r.w = acc[io][3] + bo + xr.w;
        *(float4*)(out + base) = r;
    }
}

// ---------------------------------------------------------------------------
extern "C" void kernel_launch(void* const* d_in, const int* in_sizes, int n_in,
                              void* d_out, int out_size, void* d_ws, size_t ws_size,
                              hipStream_t stream) {
    (void)in_sizes; (void)n_in; (void)out_size; (void)ws_size;
    const float* x          = (const float*)d_in[0];
    const float* ln_w       = (const float*)d_in[1];
    const float* ln_b       = (const float*)d_in[2];
    const float* log_dt     = (const float*)d_in[3];
    const float* log_A_real = (const float*)d_in[4];
    const float* A_imag     = (const float*)d_in[5];
    const float* B_re       = (const float*)d_in[6];
    const float* B_im       = (const float*)d_in[7];
    const float* C_re       = (const float*)d_in[8];
    const float* C_im       = (const float*)d_in[9];
    const float* Dv         = (const float*)d_in[10];
    const float* W          = (const float*)d_in[11];
    const float* b_out      = (const float*)d_in[12];
    float* out = (float*)d_out;
    float* ws  = (float*)d_ws;

    float* wr = ws;
    float* wi = ws + PARAM;
    float* a0 = ws + 2 * PARAM;
    float* b0 = ws + 3 * PARAM;
    float* a1 = ws + 4 * PARAM;
    float* b1 = ws + 5 * PARAM;
    float* z  = ws + 6 * PARAM;                    // B*H*L
    float* y0 = z  + (size_t)Bq * Hq * Lq;         // holds u after scan tail
    float* y1 = y0 + (size_t)Bq * Hq * Lq;

    prep_kernel<<<PARAM / 256, 256, 0, stream>>>(log_dt, log_A_real, A_imag,
                                                 B_re, B_im, C_re, C_im,
                                                 wr, wi, a0, b0, a1, b1);
    ln_kernel<<<Bq * (Lq / 64), 256, 0, stream>>>(x, ln_w, ln_b, z);
    scan_kernel<<<Bq * Hq, 64, 0, stream>>>(z, wr, wi, a0, b0, a1, b1, Dv, y0, y1);
    gemm_kernel<<<dim3(Lq / 64, Hq / 128, Bq), 256, 0, stream>>>(y0, W, b_out, x, out);
}